// Round 1
// baseline (112.007 us; speedup 1.0000x reference)
//
#include <hip/hip_runtime.h>

// Curvature stencil, (16,1024,1024) fp32, reflect boundary.
// R8: rolling 3-row window + depth-1 prefetch, #pragma unroll 1.
//   Theory: R5/R7's phased structure (load 10 rows -> compute 8 -> store)
//   holds ~110 VGPRs -> ~4 waves/SIMD, and the VMEM pipe idles during the
//   compute phase (kernel at 5.6 of 6.3 TB/s achievable). Rolling window
//   keeps only M/C/P (+1 prefetch row N) live: ~50-64 VGPR -> 8 waves/SIMD,
//   2048 blocks exactly co-resident (8 blocks/CU), and a load stays in
//   flight during every row's compute -> continuous VMEM issue.
//   - Same math, same XCD swizzle (contiguous row slab per XCD keeps the
//     2-row halo L2-resident), same nontemporal stores.
//   - Edge lanes (0/63) fix up shuffle neighbors; mid-row fallback scalar
//     loads are L1 hits (cacheline just fetched by the adjacent lane).

#define Wdim 1024
#define Hdim 1024
#define EPSf 1e-16f
#define TR 8                         // output rows per block

typedef float v4f __attribute__((ext_vector_type(4)));

__global__ __launch_bounds__(256) void curv_kernel(const float* __restrict__ u,
                                                   float* __restrict__ out) {
    int blk = ((blockIdx.x & 7) << 8) | (blockIdx.x >> 3);   // XCD swizzle
    int q  = threadIdx.x;            // float4 column, 0..255
    int w0 = q << 2;
    int rowBlk = blk & 127;          // 128 row-blocks of 8 rows per image
    int b      = blk >> 7;
    int r0     = rowBlk << 3;
    int lane   = threadIdx.x & 63;

    const float* base = u + ((size_t)b << 20);

    auto loadrow = [&](int r) -> v4f {
        return ((const v4f*)(base + (size_t)r * Wdim))[q];
    };
    // L = left neighbor (col w0-1), Rt = right neighbor (col w0+4) of row r.
    auto edges = [&](v4f R, int r, float& L, float& Rt) {
        L  = __shfl_up(R.w, 1);
        Rt = __shfl_down(R.x, 1);
        if (lane == 0)
            L = (w0 == 0) ? R.y : base[(size_t)r * Wdim + w0 - 1];   // reflect(-1)=1
        if (lane == 63)
            Rt = (w0 + 4 == Wdim) ? R.z : base[(size_t)r * Wdim + w0 + 4]; // reflect(W)=W-2
    };

    int rm = (r0 == 0) ? 1 : r0 - 1;                 // reflect(-1)=1
    v4f M = loadrow(rm);
    v4f C = loadrow(r0);
    v4f P = loadrow(r0 + 1);

    float LvM, RvM, LvC, RvC, LvP, RvP;
    edges(M, rm,     LvM, RvM);      // LvM unused (M-role rows only need Rv)
    edges(C, r0,     LvC, RvC);
    edges(P, r0 + 1, LvP, RvP);

    float* o0 = out + ((size_t)b << 20) + (size_t)r0 * Wdim;

#pragma unroll 1
    for (int j = 0; j < TR; ++j) {
        // Depth-1 prefetch of next P row; consumed only after this row's
        // compute + store, so its HBM latency hides under the VALU work.
        v4f N;
        int rp = r0 + j + 2;
        bool pre = (j < TR - 1);
        if (pre) {
            if (rp == Hdim) rp = Hdim - 2;           // reflect(H)=H-2
            N = loadrow(rp);
        }

        float c[6] = {LvC, C.x, C.y, C.z, C.w, RvC};
        float m[5] = {M.x, M.y, M.z, M.w, RvM};
        float p[5] = {LvP, P.x, P.y, P.z, P.w};

        v4f o;
#pragma unroll
        for (int i = 0; i < 4; ++i) {
            float cc   = c[i + 1];
            float cyp  = c[i + 2];
            float cym  = c[i];
            float mm   = m[i];
            float myp  = m[i + 1];
            float pp   = p[i + 1];
            float pym  = p[i];

            float dxf  = pp  - cc;
            float dxb  = cc  - mm;
            float dyf  = cyp - cc;
            float dyb  = cc  - cym;
            float dsbf = myp - mm;
            float dslf = pym - cym;

            float invF = rsqrtf(dxf * dxf + dyf * dyf + EPSf);
            float invG = rsqrtf(dxb * dxb + dsbf * dsbf + EPSf);
            float invH = rsqrtf(dslf * dslf + dyb * dyb + EPSf);

            o[i] = (dxf + dyf) * invF - dxb * invG - dyb * invH;
        }
        __builtin_nontemporal_store(o, (v4f*)(o0 + (size_t)j * Wdim) + q);

        if (pre) {
            // Rotate the window; row roles: P (needs Lv) -> C (Lv+Rv) -> M (Rv).
            M = C;  RvM = RvC;
            C = P;  LvC = LvP; RvC = RvP;
            float LvN, RvN;
            edges(N, rp, LvN, RvN);
            P = N;  LvP = LvN; RvP = RvN;
        }
    }
}

extern "C" void kernel_launch(void* const* d_in, const int* in_sizes, int n_in,
                              void* d_out, int out_size, void* d_ws, size_t ws_size,
                              hipStream_t stream) {
    const float* u = (const float*)d_in[0];
    float* out = (float*)d_out;
    // 16 images * 128 row-blocks = 2048 blocks of 256 threads
    curv_kernel<<<2048, 256, 0, stream>>>(u, out);
}

// Round 3
// 109.188 us; speedup vs baseline: 1.0258x; 1.0258x over previous
//
#include <hip/hip_runtime.h>

// Curvature stencil, (16,1024,1024) fp32, reflect boundary.
// R9 = R7 phased structure (10 row loads up front, TR=8, measured best) with
// the neighbor-exchange restructured:
//   - R8's rolling window REGRESSED (112 vs 107.7): occupancy was never the
//     limiter (10 loads in flight/wave x 16 waves/CU >> 9KB/CU needed by
//     Little's law); depth-1 prefetch killed MLP. Reverted.
//   - R9 keeps all VMEM (10 vector row loads + independent scalar edge
//     loads) issued before any dependent op, but moves the 19 shuffles and
//     lane-0/63 fixups INTO the per-row loop: row j's compute only waits on
//     rows j..j+2's shuffles (progressive lgkmcnt) instead of a 19-deep DS
//     drain + divergent branch before the first FLOP. Full unroll lets the
//     compiler CSE adjacent rows' shared shuffles (still 19 total).
//   - XCD swizzle: each XCD owns 2 whole images -> halo rows L2-resident.
//   - Nontemporal float4 stores.
// (R10 = R9 resubmitted; previous bench died to a container-infra failure,
//  no measurement was taken.)

#define Wdim 1024
#define Hdim 1024
#define EPSf 1e-16f
#define TR 8                         // tile rows

typedef float v4f __attribute__((ext_vector_type(4)));

__global__ __launch_bounds__(256) void curv_kernel(const float* __restrict__ u,
                                                   float* __restrict__ out) {
    int blk = ((blockIdx.x & 7) << 8) | (blockIdx.x >> 3);   // XCD swizzle
    int q  = threadIdx.x;            // float4 column, 0..255
    int w0 = q << 2;
    int rowBlk = blk & 127;          // 128 row-blocks of 8 rows per image
    int b      = blk >> 7;
    int r0     = rowBlk << 3;
    int lane   = threadIdx.x & 63;

    const float* base = u + ((size_t)b << 20);

    int rIdx[TR + 2];
    rIdx[0] = (r0 == 0) ? 1 : r0 - 1;                    // reflect(-1)=1
#pragma unroll
    for (int k = 1; k <= TR; ++k) rIdx[k] = r0 + k - 1;
    rIdx[TR + 1] = (r0 + TR == Hdim) ? Hdim - 2 : r0 + TR;  // reflect(H)=H-2

    v4f R[TR + 2];
#pragma unroll
    for (int k = 0; k < TR + 2; ++k)
        R[k] = ((const v4f*)(base + (size_t)rIdx[k] * Wdim))[q];

    // Independent scalar edge loads for mid-row wave boundaries, issued
    // alongside the row loads (no dependence on R[]). Only lanes 0/63 use
    // them; image-edge reflect cases are handled from R[] in the loop.
    float eL[TR + 2], eR[TR + 2];
    bool midL = (lane == 0)  && (w0 != 0);
    bool midR = (lane == 63) && (w0 + 4 != Wdim);
    if (midL) {
#pragma unroll
        for (int k = 1; k < TR + 2; ++k)
            eL[k] = base[(size_t)rIdx[k] * Wdim + w0 - 1];
    }
    if (midR) {
#pragma unroll
        for (int k = 0; k < TR + 1; ++k)
            eR[k] = base[(size_t)rIdx[k] * Wdim + w0 + 4];
    }

    size_t obase = ((size_t)b << 20) + (size_t)r0 * Wdim;
#pragma unroll
    for (int j = 0; j < TR; ++j) {
        v4f C = R[1 + j];
        v4f M = R[j];
        v4f P = R[2 + j];

        // Per-row neighbor exchange; adjacent iterations share shuffles
        // (LvP at j == LvC at j+1), CSE'd by the full unroll.
        float LvC = __shfl_up(C.w, 1);
        float LvP = __shfl_up(P.w, 1);
        float RvC = __shfl_down(C.x, 1);
        float RvM = __shfl_down(M.x, 1);
        if (lane == 0) {             // left neighbor of col w0
            LvC = midL ? eL[1 + j] : C.y;   // reflect(-1)=1 -> .y
            LvP = midL ? eL[2 + j] : P.y;
        }
        if (lane == 63) {            // right neighbor of col w0+3
            RvC = midR ? eR[1 + j] : C.z;   // reflect(W)=W-2 -> .z
            RvM = midR ? eR[j]     : M.z;
        }

        float c[6] = {LvC, C.x, C.y, C.z, C.w, RvC};
        float m[5] = {M.x, M.y, M.z, M.w, RvM};
        float p[5] = {LvP, P.x, P.y, P.z, P.w};

        v4f o;
#pragma unroll
        for (int i = 0; i < 4; ++i) {
            float cc   = c[i + 1];
            float cyp  = c[i + 2];
            float cym  = c[i];
            float mm   = m[i];
            float myp  = m[i + 1];
            float pp   = p[i + 1];
            float pym  = p[i];

            float dxf  = pp  - cc;
            float dxb  = cc  - mm;
            float dyf  = cyp - cc;
            float dyb  = cc  - cym;
            float dsbf = myp - mm;
            float dslf = pym - cym;

            float invF = rsqrtf(dxf * dxf + dyf * dyf + EPSf);
            float invG = rsqrtf(dxb * dxb + dsbf * dsbf + EPSf);
            float invH = rsqrtf(dslf * dslf + dyb * dyb + EPSf);

            o[i] = (dxf + dyf) * invF - dxb * invG - dyb * invH;
        }
        __builtin_nontemporal_store(o, (v4f*)(out + obase + (size_t)j * Wdim) + q);
    }
}

extern "C" void kernel_launch(void* const* d_in, const int* in_sizes, int n_in,
                              void* d_out, int out_size, void* d_ws, size_t ws_size,
                              hipStream_t stream) {
    const float* u = (const float*)d_in[0];
    float* out = (float*)d_out;
    // 16 images * 128 row-blocks = 2048 blocks of 256 threads
    curv_kernel<<<2048, 256, 0, stream>>>(u, out);
}